// Round 4
// baseline (192.429 us; speedup 1.0000x reference)
//
#include <hip/hip_runtime.h>
#include <stdint.h>
#include <stddef.h>

#define MDIM 2048
#define KDIM 4096
#define NDIM 4096
// group size G = 128 along K; K-tiles of 32 -> group = kt>>2 (never straddles)

using bf16x8 = __attribute__((ext_vector_type(8))) short;   // one MFMA frag / lane
using f32x4  = __attribute__((ext_vector_type(4))) float;   // MFMA accumulator

// fp32 -> bf16 (round-to-nearest-even), bit pattern in short
__device__ __forceinline__ short f2bf(float f) {
    union { float f; uint32_t u; } v; v.f = f;
    return (short)((v.u + 0x7fffu + ((v.u >> 16) & 1u)) >> 16);
}

// ---------------------------------------------------------------------------
// Prep (one dispatch): build FRAGMENT-MAJOR operands so the GEMM can load
// MFMA fragments straight from global memory (no LDS round-trip).
//   A-frags: xf[(mt*128 + kt)*64 + lane] = 16 B frag, lane l holds
//            x_bf16[mt*16 + (l&15)][kt*32 + (l>>4)*8 .. +8)
//   W-frags: wf[(nt*128 + kt)*64 + lane], same layout over dequantized W.
// Writes are perfectly lane-contiguous (1 KB/wave). Reads are 16-32 B/lane
// granules that tile full cache lines collectively (L1 absorbs the split).
//   blocks [0,4096):      A  (128 mt x 128 kt frags)
//   blocks [4096,12288):  W  (256 nt x 128 kt frags), int4 dequant fused
// ---------------------------------------------------------------------------
__global__ __launch_bounds__(256) void prep(const float* __restrict__ x,
                                            const int* __restrict__ Bq,
                                            const float* __restrict__ s,
                                            bf16x8* __restrict__ xf,
                                            bf16x8* __restrict__ wf) {
    const int b = blockIdx.x, tid = threadIdx.x;
    if (b < 4096) {
        int t  = b * 256 + tid;
        int l  = t & 63, f = t >> 6;
        int kt = f & 127, mt = f >> 7;
        int m  = mt * 16 + (l & 15);
        int k0 = kt * 32 + (l >> 4) * 8;
        const float* p = x + (size_t)m * KDIM + k0;
        float4 a = *(const float4*)p;
        float4 c = *(const float4*)(p + 4);
        bf16x8 o;
        o[0] = f2bf(a.x); o[1] = f2bf(a.y); o[2] = f2bf(a.z); o[3] = f2bf(a.w);
        o[4] = f2bf(c.x); o[5] = f2bf(c.y); o[6] = f2bf(c.z); o[7] = f2bf(c.w);
        xf[t] = o;
    } else {
        int t  = (b - 4096) * 256 + tid;
        int l  = t & 63, f = t >> 6;
        int kt = f & 127, nt = f >> 7;
        int n  = nt * 16 + (l & 15);
        int k0 = kt * 32 + (l >> 4) * 8;
        int sh = (n & 7) * 4;
        const int* p = Bq + (size_t)(n >> 3) * KDIM + k0;
        int4 p0 = *(const int4*)p;
        int4 p1 = *(const int4*)(p + 4);
        float sc = s[(kt >> 2) * NDIM + n];   // group = kt>>2, const per frag
        bf16x8 o;
        o[0] = f2bf((float)(((p0.x >> sh) & 0xF) - 8) * sc);
        o[1] = f2bf((float)(((p0.y >> sh) & 0xF) - 8) * sc);
        o[2] = f2bf((float)(((p0.z >> sh) & 0xF) - 8) * sc);
        o[3] = f2bf((float)(((p0.w >> sh) & 0xF) - 8) * sc);
        o[4] = f2bf((float)(((p1.x >> sh) & 0xF) - 8) * sc);
        o[5] = f2bf((float)(((p1.y >> sh) & 0xF) - 8) * sc);
        o[6] = f2bf((float)(((p1.z >> sh) & 0xF) - 8) * sc);
        o[7] = f2bf((float)(((p1.w >> sh) & 0xF) - 8) * sc);
        wf[t] = o;
    }
}

// ---------------------------------------------------------------------------
// LDS-free GEMM: C = A * W^T from fragment-major operands.
// 256 threads = 4 waves (2x2), wave tile 64x64 = 4x4 16x16x32 MFMA.
// Block tile 128x128, grid (16 bm, 32 bn) = 512 blocks, 2 blocks/CU.
// No __shared__, no barriers: latency hidden by a 4-stage rotating register
// pipeline (frags for kt+1..kt+4 in flight; ~3x16 MFMA between load & use).
// Dispatch order x+16y => all 32 blocks sharing an A-panel land on XCD x%8
// (L2-local A); waves pair-share frags within a block (L1 hits).
// C/D layout: col = lane&15, row = (lane>>4)*4 + reg  (m89/m91 verified).
// ---------------------------------------------------------------------------
__global__ __launch_bounds__(256) void gemm_frag(const bf16x8* __restrict__ Af,
                                                 const bf16x8* __restrict__ Wf,
                                                 float* __restrict__ C) {
    const int tid  = threadIdx.x;
    const int lane = tid & 63;
    const int wave = tid >> 6;
    const int mt0 = blockIdx.x * 8 + (wave >> 1) * 4;   // 4 m-tiles of 16
    const int nt0 = blockIdx.y * 8 + (wave & 1) * 4;    // 4 n-tiles of 16

    const bf16x8* pa[4];
    const bf16x8* pw[4];
#pragma unroll
    for (int i = 0; i < 4; i++) {
        pa[i] = Af + (size_t)(mt0 + i) * 128 * 64 + lane;
        pw[i] = Wf + (size_t)(nt0 + i) * 128 * 64 + lane;
    }

    f32x4 acc[4][4] = {};
    bf16x8 ab[4][4], bb[4][4];     // 4-stage rotating fragment buffers

#pragma unroll
    for (int st = 0; st < 4; st++)
#pragma unroll
        for (int i = 0; i < 4; i++) {
            ab[st][i] = pa[i][st * 64];
            bb[st][i] = pw[i][st * 64];
        }

    for (int kt = 0; kt < 128; kt += 4) {
#pragma unroll
        for (int st = 0; st < 4; st++) {
#pragma unroll
            for (int i = 0; i < 4; i++)
#pragma unroll
                for (int j = 0; j < 4; j++)
                    acc[i][j] = __builtin_amdgcn_mfma_f32_16x16x32_bf16(
                        ab[st][i], bb[st][j], acc[i][j], 0, 0, 0);
            const int knext = kt + 4 + st;
            if (knext < 128) {
#pragma unroll
                for (int i = 0; i < 4; i++) {
                    ab[st][i] = pa[i][knext * 64];
                    bb[st][i] = pw[i][knext * 64];
                }
            }
        }
    }

    // epilogue: D[row = (lane>>4)*4 + r][col = lane&15], direct stores
    const int fr = lane & 15;
    const int rr = (lane >> 4) * 4;
#pragma unroll
    for (int i = 0; i < 4; i++)
#pragma unroll
        for (int j = 0; j < 4; j++) {
            const int row0 = (mt0 + i) * 16 + rr;
            const int col  = (nt0 + j) * 16 + fr;
#pragma unroll
            for (int r = 0; r < 4; r++)
                C[(size_t)(row0 + r) * NDIM + col] = acc[i][j][r];
        }
}

// ---------------------------------------------------------------------------
extern "C" void kernel_launch(void* const* d_in, const int* in_sizes, int n_in,
                              void* d_out, int out_size, void* d_ws, size_t ws_size,
                              hipStream_t stream) {
    const float* x  = (const float*)d_in[0];
    const int*   Bq = (const int*)d_in[1];
    const float* s  = (const float*)d_in[2];
    float* out = (float*)d_out;

    // workspace: [0,16MB) A frags, [16MB,48MB) W frags (bf16, frag-major)
    bf16x8* xf = (bf16x8*)d_ws;
    bf16x8* wf = xf + (size_t)MDIM * KDIM / 8;

    hipLaunchKernelGGL(prep, dim3(12288), dim3(256), 0, stream,
                       x, Bq, s, xf, wf);
    hipLaunchKernelGGL(gemm_frag, dim3(MDIM / 128, NDIM / 128), dim3(256),
                       0, stream, xf, wf, out);
}